// Round 1
// baseline (12.092 us; speedup 1.0000x reference)
//
#include <hip/hip_runtime.h>
#include <math.h>

// Problem constants (fixed by the reference).
constexpr int S_ = 64;
constexpr int I_ = 128;
constexpr int PAIRS = I_ * I_;                  // 16384 per s
constexpr int TILES = 8;                        // blocks per s
constexpr int PAIRS_PER_TILE = PAIRS / TILES;   // 2048
constexpr int THREADS = 256;
constexpr int PAIRS_PER_THREAD = PAIRS_PER_TILE / THREADS;  // 8

__global__ __launch_bounds__(THREADS) void diffdist_kernel(
    const float* __restrict__ f1,   // [S,I,3] fcoords1
    const float* __restrict__ f2,   // [S,I,3] fcoords2
    const float* __restrict__ M,    // [S,3,3]
    float* __restrict__ out)        // [S*I*I] dists ++ [S*I*3] cart_coords
{
    const int s    = blockIdx.x >> 3;          // blockIdx.x / TILES
    const int tile = blockIdx.x & (TILES - 1);
    const int tid  = threadIdx.x;

    __shared__ float sm[9];
    __shared__ float c1[I_][3];   // cart1 = frac(f1) @ M
    __shared__ float c2[I_][3];   // cart2 = frac(f2) @ M

    if (tid < 9) sm[tid] = M[s * 9 + tid];
    __syncthreads();

    // Staging: threads 0..127 build cart1 rows, 128..255 build cart2 rows.
    {
        const int row = tid & (I_ - 1);
        const float* fsrc = (tid < I_) ? f1 : f2;
        const float* p = fsrc + (size_t)(s * I_ + row) * 3;
        float a = p[0]; a -= floorf(a);
        float b = p[1]; b -= floorf(b);
        float g = p[2]; g -= floorf(g);
        float x = a * sm[0] + b * sm[3] + g * sm[6];
        float y = a * sm[1] + b * sm[4] + g * sm[7];
        float z = a * sm[2] + b * sm[5] + g * sm[8];
        if (tid < I_) {
            c1[row][0] = x; c1[row][1] = y; c1[row][2] = z;
            if (tile == 0) {
                // second output: cart_coords = cart1
                float* o2 = out + (size_t)S_ * PAIRS + (size_t)(s * I_ + row) * 3;
                o2[0] = x; o2[1] = y; o2[2] = z;
            }
        } else {
            c2[row][0] = x; c2[row][1] = y; c2[row][2] = z;
        }
    }
    __syncthreads();

    // Matrix rows in registers (wave-uniform values).
    const float m00 = sm[0], m01 = sm[1], m02 = sm[2];
    const float m10 = sm[3], m11 = sm[4], m12 = sm[5];
    const float m20 = sm[6], m21 = sm[7], m22 = sm[8];

    float* od = out + (size_t)s * PAIRS;

    #pragma unroll
    for (int p = 0; p < PAIRS_PER_THREAD; ++p) {
        const int gidx = tile * PAIRS_PER_TILE + p * THREADS + tid;
        const int i = gidx >> 7;          // fcoords2 index
        const int j = gidx & (I_ - 1);    // fcoords1 index

        const float bx = c2[i][0] - c1[j][0];
        const float by = c2[i][1] - c1[j][1];
        const float bz = c2[i][2] - c1[j][2];

        float best = 3.4e38f;
        // min over 27 images: d = b + ia*M0 + ib*M1 + ic*M2, ia/ib/ic in {-1,0,1}.
        // Fully unrolled: the +-1/0 coefficients fold to add/sub/copy.
        #pragma unroll
        for (int ia = -1; ia <= 1; ++ia) {
            const float fa = (float)ia;
            const float ax = fmaf(fa, m00, bx);
            const float ay = fmaf(fa, m01, by);
            const float az = fmaf(fa, m02, bz);
            #pragma unroll
            for (int ib = -1; ib <= 1; ++ib) {
                const float fb = (float)ib;
                const float ux = fmaf(fb, m10, ax);
                const float uy = fmaf(fb, m11, ay);
                const float uz = fmaf(fb, m12, az);
                #pragma unroll
                for (int ic = -1; ic <= 1; ++ic) {
                    const float fc = (float)ic;
                    const float vx = fmaf(fc, m20, ux);
                    const float vy = fmaf(fc, m21, uy);
                    const float vz = fmaf(fc, m22, uz);
                    const float d = fmaf(vx, vx, fmaf(vy, vy, vz * vz));
                    best = fminf(best, d);
                }
            }
        }
        od[gidx] = sqrtf(best + 1e-10f);
    }
}

extern "C" void kernel_launch(void* const* d_in, const int* in_sizes, int n_in,
                              void* d_out, int out_size, void* d_ws, size_t ws_size,
                              hipStream_t stream) {
    const float* f1 = (const float*)d_in[0];   // fcoords1 [S,I,3]
    const float* f2 = (const float*)d_in[1];   // fcoords2 [S,I,3]
    const float* M  = (const float*)d_in[2];   // matrix   [S,3,3]
    float* out = (float*)d_out;

    dim3 grid(S_ * TILES);
    dim3 block(THREADS);
    diffdist_kernel<<<grid, block, 0, stream>>>(f1, f2, M, out);
}

// Round 2
// 10.695 us; speedup vs baseline: 1.1306x; 1.1306x over previous
//
#include <hip/hip_runtime.h>
#include <math.h>

// Problem constants (fixed by the reference).
constexpr int S_ = 64;
constexpr int I_ = 128;
constexpr int PAIRS = I_ * I_;                  // 16384 per s
constexpr int TILES = 8;                        // blocks per s
constexpr int PAIRS_PER_TILE = PAIRS / TILES;   // 2048
constexpr int THREADS = 256;
constexpr int PPT = PAIRS_PER_TILE / THREADS;   // 8 pairs per thread

__device__ __forceinline__ float rfl(float x) {
    // Force a wave-uniform value into an SGPR.
    return __int_as_float(__builtin_amdgcn_readfirstlane(__float_as_int(x)));
}

__global__ __launch_bounds__(THREADS) void diffdist_kernel(
    const float* __restrict__ f1,   // [S,I,3] fcoords1
    const float* __restrict__ f2,   // [S,I,3] fcoords2
    const float* __restrict__ M,    // [S,3,3]
    float* __restrict__ out)        // [S*I*I] dists ++ [S*I*3] cart_coords
{
    const int s    = blockIdx.x >> 3;          // blockIdx.x / TILES
    const int tile = blockIdx.x & (TILES - 1);
    const int tid  = threadIdx.x;

    __shared__ float c1[I_][3];   // cart1 = frac(f1) @ M
    __shared__ float c2[I_][3];   // cart2 = frac(f2) @ M

    // Matrix rows in registers; 9 scalar loads broadcast through L1.
    const float* Ms = M + s * 9;
    const float m00 = Ms[0], m01 = Ms[1], m02 = Ms[2];
    const float m10 = Ms[3], m11 = Ms[4], m12 = Ms[5];
    const float m20 = Ms[6], m21 = Ms[7], m22 = Ms[8];

    // Staging: threads 0..127 build cart1 rows, 128..255 build cart2 rows.
    {
        const int row = tid & (I_ - 1);
        const float* fsrc = (tid < I_) ? f1 : f2;
        const float* p = fsrc + (size_t)(s * I_ + row) * 3;
        float a = p[0]; a -= floorf(a);
        float b = p[1]; b -= floorf(b);
        float g = p[2]; g -= floorf(g);
        float x = fmaf(a, m00, fmaf(b, m10, g * m20));
        float y = fmaf(a, m01, fmaf(b, m11, g * m21));
        float z = fmaf(a, m02, fmaf(b, m12, g * m22));
        if (tid < I_) {
            c1[row][0] = x; c1[row][1] = y; c1[row][2] = z;
            if (tile == 0) {
                // second output: cart_coords = cart1
                float* o2 = out + (size_t)S_ * PAIRS + (size_t)(s * I_ + row) * 3;
                o2[0] = x; o2[1] = y; o2[2] = z;
            }
        } else {
            c2[row][0] = x; c2[row][1] = y; c2[row][2] = z;
        }
    }

    // 13 representative image offsets; the other 13 are their negations,
    // and the 27th (0,0,0) is handled by best=0 init.
    constexpr int IA[13] = {0, 0, 0, 0,  1,  1, 1,  1, 1, 1,  1, 1, 1};
    constexpr int IB[13] = {0, 1, 1, 1, -1, -1,-1,  0, 0, 0,  1, 1, 1};
    constexpr int IC[13] = {1,-1, 0, 1, -1,  0, 1, -1, 0, 1, -1, 0, 1};

    // Per-s wave-uniform constants: T2 = 2*t, C = |t|^2, t = ia*M0+ib*M1+ic*M2.
    // Pushed to SGPRs so the inner fma reads exactly one SGPR operand.
    float t2x[13], t2y[13], t2z[13], cc[13];
    #pragma unroll
    for (int m = 0; m < 13; ++m) {
        const float fa = (float)IA[m], fb = (float)IB[m], fc = (float)IC[m];
        const float tx = fa * m00 + fb * m10 + fc * m20;
        const float ty = fa * m01 + fb * m11 + fc * m21;
        const float tz = fa * m02 + fb * m12 + fc * m22;
        cc[m]  = rfl(fmaf(tx, tx, fmaf(ty, ty, tz * tz)));
        t2x[m] = rfl(tx + tx);
        t2y[m] = rfl(ty + ty);
        t2z[m] = rfl(tz + tz);
    }

    __syncthreads();

    // j (fcoords1 row) is constant per thread; i advances by 2 per p-iter.
    const int j  = tid & (I_ - 1);
    const int hi = tid >> 7;
    const float c1x = c1[j][0], c1y = c1[j][1], c1z = c1[j][2];

    float* od = out + (size_t)s * PAIRS + tile * PAIRS_PER_TILE;

    #pragma unroll
    for (int p = 0; p < PPT; ++p) {
        const int ii = tile * 16 + p * 2 + hi;     // wave-uniform LDS row
        const float bx = c2[ii][0] - c1x;
        const float by = c2[ii][1] - c1y;
        const float bz = c2[ii][2] - c1z;
        const float n  = fmaf(bx, bx, fmaf(by, by, bz * bz));

        // best' = min over images of (d^2 - |b|^2); zero image contributes 0.
        float best = 0.0f;
        #pragma unroll
        for (int m = 0; m < 13; ++m) {
            const float u  = fmaf(bx, t2x[m], fmaf(by, t2y[m], bz * t2z[m]));
            const float d1 = cc[m] + u;   // image +m
            const float d2 = cc[m] - u;   // image -m
            best = fminf(best, fminf(d1, d2));   // -> v_min3_f32
        }
        od[p * THREADS + tid] = sqrtf(fmaxf(n + best, 0.0f) + 1e-10f);
    }
}

extern "C" void kernel_launch(void* const* d_in, const int* in_sizes, int n_in,
                              void* d_out, int out_size, void* d_ws, size_t ws_size,
                              hipStream_t stream) {
    const float* f1 = (const float*)d_in[0];   // fcoords1 [S,I,3]
    const float* f2 = (const float*)d_in[1];   // fcoords2 [S,I,3]
    const float* M  = (const float*)d_in[2];   // matrix   [S,3,3]
    float* out = (float*)d_out;

    dim3 grid(S_ * TILES);
    dim3 block(THREADS);
    diffdist_kernel<<<grid, block, 0, stream>>>(f1, f2, M, out);
}